// Round 3
// baseline (864.906 us; speedup 1.0000x reference)
//
#include <hip/hip_runtime.h>
#include <math.h>

#define TT 24
#define SS 200
#define CIN 8
#define CW 32
#define NSC 6400      // SS*CW
#define NTOT 153600   // TT*SS*CW
#define NBLK 600

// smem layout (floats)
#define HOFF   32     // H (3*1024) in finale; X-slab (6400) in spatial
#define W1OFF  3104
#define W2OFF  4384
#define B1OFF  5408
#define B2OFF  5440
#define SXOFF  5472
#define SP1OFF 5728
#define SP2OFF 5984
#define SXTOFF 6240
#define SHOFF  6496
#define SXINOFF 6752
#define SMEMSZ 6816   // 27.3 KB

__global__ void k_barinit(unsigned* bar) {
    bar[0] = 0u;   // arrive counter
    bar[1] = 0u;   // generation
}

// Manual grid barrier: release fence -> arrive -> (last resets & bumps gen |
// others spin on gen) -> acquire fence. Device-scope atomics are cross-XCD
// coherent; __threadfence() emits the L2 writeback/invalidate gfx950 needs.
__device__ __forceinline__ void gridbar(unsigned* cnt, unsigned* gen, unsigned* lgen) {
    __syncthreads();
    if (threadIdx.x == 0) {
        __threadfence();   // release all prior writes device-wide
        const unsigned g = *lgen;
        if (__hip_atomic_fetch_add(cnt, 1u, __ATOMIC_ACQ_REL, __HIP_MEMORY_SCOPE_AGENT) == NBLK - 1u) {
            __hip_atomic_store(cnt, 0u, __ATOMIC_RELAXED, __HIP_MEMORY_SCOPE_AGENT);
            __hip_atomic_fetch_add(gen, 1u, __ATOMIC_RELEASE, __HIP_MEMORY_SCOPE_AGENT);
        } else {
            unsigned spins = 0;
            while (__hip_atomic_load(gen, __ATOMIC_ACQUIRE, __HIP_MEMORY_SCOPE_AGENT) <= g) {
                __builtin_amdgcn_s_sleep(8);
                if (++spins > (1u << 24)) break;   // hang-safety escape
            }
        }
        *lgen = g + 1u;
        __threadfence();   // acquire: subsequent reads see remote writes
    }
    __syncthreads();
}

__global__ __launch_bounds__(256, 3)
void gtcnn(const float* __restrict__ xin, const float* __restrict__ At,
           const float* __restrict__ As, const float* __restrict__ H,
           const float* __restrict__ svec, const float* __restrict__ Wf,
           const float* __restrict__ bf, const float* __restrict__ Wl,
           const float* __restrict__ bl, const float* __restrict__ mW1,
           const float* __restrict__ mb1, const float* __restrict__ mW2,
           const float* __restrict__ mb2, float* __restrict__ out,
           float* __restrict__ ws)
{
    __shared__ float smem[SMEMSZ];

    unsigned* cnt = (unsigned*)ws;
    unsigned* gen = (unsigned*)ws + 1;
    float* dinv_t = ws + 64;       // 24
    float* dinv_s = ws + 96;       // 200
    float* X  = ws + 320;          // 153600 (updated in place)
    float* Y  = X  + NTOT;
    float* B1 = Y  + NTOT;
    float* Y2 = B1 + NTOT;

    unsigned lgen = 0;

    const int tid = threadIdx.x;
    const int bid = blockIdx.x;
    const int gid = bid*256 + tid;     // 0..153599, == element index
    const int t   = bid / 25;          // 25 blocks per t-slab
    const int sg  = bid % 25;
    const int sc  = sg*256 + tid;      // s*32+c within the t-slab
    const int idx = t*NSC + sc;        // == gid
    const int r   = tid >> 5;          // local s (0..7)
    const int c   = tid & 31;          // channel
    const int s   = sg*8 + r;          // global s (0..199)

    // ---------------- P0: dinv_t, dinv_s, X = xin@Wf + bf ----------------
    {
        const int wid = gid >> 6, lane = gid & 63;
        if (wid < TT) {
            float v = (lane < TT) ? At[wid*TT + lane] : 0.f;
            #pragma unroll
            for (int off = 32; off; off >>= 1) v += __shfl_xor(v, off, 64);
            if (lane == 0) dinv_t[wid] = 1.f / sqrtf(v);
        } else if (wid < TT + SS) {
            const int row = wid - TT;
            float v = 0.f;
            for (int j = lane; j < SS; j += 64) v += As[row*SS + j];
            #pragma unroll
            for (int off = 32; off; off >>= 1) v += __shfl_xor(v, off, 64);
            if (lane == 0) dinv_s[row] = 1.f / sqrtf(v);
        }
        const int n = gid >> 5;
        float acc = bf[c];
        #pragma unroll
        for (int i = 0; i < CIN; ++i) acc += xin[n*CIN + i] * Wf[i*CW + c];
        X[gid] = acc;
    }
    gridbar(cnt, gen, &lgen);

    for (int b = 0; b < 2; ++b) {
        const float s0 = svec[b*4+0], s1 = svec[b*4+1];
        const float s2 = svec[b*4+2], s3 = svec[b*4+3];
        const float* Hb = H   + b*3*CW*CW;
        const float* W1 = mW1 + b*(CW+CIN)*CW;
        const float* b1 = mb1 + b*CW;
        const float* W2 = mW2 + b*CW*CW;
        const float* b2 = mb2 + b*CW;

        // ---------------- P1: Y = Ãs X  (dinv folded at staging) ----------------
        for (int i = tid; i < NSC; i += 256)
            smem[HOFF + i] = X[t*NSC + i] * dinv_s[i >> 5];
        __syncthreads();
        {
            const float4* arow = (const float4*)(As + s*SS);
            float acc = 0.f;
            #pragma unroll 5
            for (int q = 0; q < SS/4; ++q) {
                float4 a = arow[q];
                acc += a.x * smem[HOFF + (4*q+0)*CW + c];
                acc += a.y * smem[HOFF + (4*q+1)*CW + c];
                acc += a.z * smem[HOFF + (4*q+2)*CW + c];
                acc += a.w * smem[HOFF + (4*q+3)*CW + c];
            }
            Y[idx] = 0.5f * dinv_s[s] * acc;
        }
        gridbar(cnt, gen, &lgen);

        // ---------------- P2: B1 = s0*X + s1*Y + s2*Ât X + s3*Ât Y ----------------
        if (tid < TT) smem[tid] = At[t*TT + tid] * dinv_t[t] * dinv_t[tid] * 0.5f;
        __syncthreads();
        {
            float z = 0.f, w = 0.f;
            #pragma unroll
            for (int tp = 0; tp < TT; ++tp) {
                const float a = smem[tp];
                z += a * X[tp*NSC + sc];
                w += a * Y[tp*NSC + sc];
            }
            B1[idx] = s0*X[idx] + s1*Y[idx] + s2*z + s3*w;
        }
        gridbar(cnt, gen, &lgen);

        // ---------------- P3: Y2 = Ãs B1 ----------------
        for (int i = tid; i < NSC; i += 256)
            smem[HOFF + i] = B1[t*NSC + i] * dinv_s[i >> 5];
        __syncthreads();
        {
            const float4* arow = (const float4*)(As + s*SS);
            float acc = 0.f;
            #pragma unroll 5
            for (int q = 0; q < SS/4; ++q) {
                float4 a = arow[q];
                acc += a.x * smem[HOFF + (4*q+0)*CW + c];
                acc += a.y * smem[HOFF + (4*q+1)*CW + c];
                acc += a.z * smem[HOFF + (4*q+2)*CW + c];
                acc += a.w * smem[HOFF + (4*q+3)*CW + c];
            }
            Y2[idx] = 0.5f * dinv_s[s] * acc;
        }
        gridbar(cnt, gen, &lgen);

        // ---------------- P4: temporal2 + epilogue (+ last for b==1) --------------
        // smem[0..23] still holds the Ât row staged in P2 (P3 only wrote HOFF+).
        for (int i = tid; i < 3*CW*CW; i += 256) smem[HOFF + i]  = Hb[i];
        for (int i = tid; i < (CW+CIN)*CW; i += 256) smem[W1OFF + i] = W1[i];
        for (int i = tid; i < CW*CW; i += 256) smem[W2OFF + i] = W2[i];
        if (tid < CW) { smem[B1OFF + tid] = b1[tid]; smem[B2OFF + tid] = b2[tid]; }
        {
            float z = 0.f, w = 0.f;
            #pragma unroll
            for (int tp = 0; tp < TT; ++tp) {
                const float a = smem[tp];
                z += a * B1[tp*NSC + sc];
                w += a * Y2[tp*NSC + sc];
            }
            const float p2 = s0*B1[idx] + s1*Y2[idx] + s2*z + s3*w;
            smem[SXOFF + tid]  = X[idx];
            smem[SP1OFF + tid] = B1[idx];
            smem[SP2OFF + tid] = p2;
            if (c < CIN) smem[SXINOFF + r*CIN + c] = xin[(idx >> 5)*CIN + c];
        }
        __syncthreads();
        {
            float acc = 0.f;
            #pragma unroll 8
            for (int cp = 0; cp < CW; ++cp) {
                acc += smem[SXOFF  + r*CW + cp] * smem[HOFF + cp*CW + c];
                acc += smem[SP1OFF + r*CW + cp] * smem[HOFF + CW*CW + cp*CW + c];
                acc += smem[SP2OFF + r*CW + cp] * smem[HOFF + 2*CW*CW + cp*CW + c];
            }
            smem[SXTOFF + tid] = tanhf(acc);
        }
        __syncthreads();
        {
            float h = smem[B1OFF + c];
            #pragma unroll 8
            for (int cp = 0; cp < CW; ++cp)
                h += smem[SXTOFF + r*CW + cp] * smem[W1OFF + cp*CW + c];
            #pragma unroll
            for (int i = 0; i < CIN; ++i)
                h += smem[SXINOFF + r*CIN + i] * smem[W1OFF + (CW+i)*CW + c];
            smem[SHOFF + tid] = fmaxf(h, 0.f);
        }
        __syncthreads();
        {
            float xn = smem[B2OFF + c];
            #pragma unroll 8
            for (int cp = 0; cp < CW; ++cp)
                xn += smem[SHOFF + r*CW + cp] * smem[W2OFF + cp*CW + c];
            if (b == 0) {
                X[idx] = xn;
            } else {
                float v = xn * Wl[c];
                #pragma unroll
                for (int off = 16; off; off >>= 1) v += __shfl_xor(v, off, 64);
                if (c == 0) out[idx >> 5] = v + bl[0];
            }
        }
        if (b == 0) gridbar(cnt, gen, &lgen);
    }
}

extern "C" void kernel_launch(void* const* d_in, const int* in_sizes, int n_in,
                              void* d_out, int out_size, void* d_ws, size_t ws_size,
                              hipStream_t stream) {
    const float* xin   = (const float*)d_in[0];
    const float* Adj_t = (const float*)d_in[1];
    const float* Adj_s = (const float*)d_in[2];
    const float* H     = (const float*)d_in[3];
    const float* svec  = (const float*)d_in[4];
    const float* Wf    = (const float*)d_in[5];
    const float* bf    = (const float*)d_in[6];
    const float* Wl    = (const float*)d_in[7];
    const float* bl    = (const float*)d_in[8];
    const float* mW1   = (const float*)d_in[9];
    const float* mb1   = (const float*)d_in[10];
    const float* mW2   = (const float*)d_in[11];
    const float* mb2   = (const float*)d_in[12];
    float* out = (float*)d_out;
    float* ws  = (float*)d_ws;

    k_barinit<<<1, 1, 0, stream>>>((unsigned*)ws);
    gtcnn<<<NBLK, 256, 0, stream>>>(xin, Adj_t, Adj_s, H, svec, Wf, bf,
                                    Wl, bl, mW1, mb1, mW2, mb2, out, ws);
}

// Round 4
// 511.908 us; speedup vs baseline: 1.6896x; 1.6896x over previous
//
#include <hip/hip_runtime.h>
#include <math.h>

#define TT 24
#define SS 200
#define CIN 8
#define CW 32
#define NSC 6400      // SS*CW
#define NTOT 153600   // TT*SS*CW
#define NBLK 600

// smem layout (floats)
#define HOFF   32     // H (3*1024) in finale; X-slab (6400) in spatial
#define W1OFF  3104
#define W2OFF  4384
#define B1OFF  5408
#define B2OFF  5440
#define SXOFF  5472
#define SP1OFF 5728
#define SP2OFF 5984
#define SXTOFF 6240
#define SHOFF  6496
#define SXINOFF 6752
#define SMEMSZ 6816   // 27.3 KB

__global__ void k_barinit(unsigned* bar) {
    bar[0] = 0u;   // monotonic arrive counter
}

// Monotonic-counter grid barrier.
// Release fence (L2 writeback) once -> relaxed arrive -> relaxed spin (no
// per-poll cache invalidate!) -> acquire fence (L1/L2 inv) once.
// R3's bug: ACQUIRE on every spin-poll = cache-invalidate storm (92 MB HBM
// refetch, 865 us). Relaxed atomics are still per-location coherent at agent
// scope, so the spin observes the remote increments without invalidating.
__device__ __forceinline__ void gridbar(unsigned* cnt, unsigned* lbar) {
    __syncthreads();
    if (threadIdx.x == 0) {
        __builtin_amdgcn_fence(__ATOMIC_RELEASE, "agent");
        __hip_atomic_fetch_add(cnt, 1u, __ATOMIC_RELAXED, __HIP_MEMORY_SCOPE_AGENT);
        const unsigned target = (++(*lbar)) * NBLK;
        unsigned spins = 0;
        while (__hip_atomic_load(cnt, __ATOMIC_RELAXED, __HIP_MEMORY_SCOPE_AGENT) < target) {
            __builtin_amdgcn_s_sleep(2);
            if (++spins > (1u << 20)) break;   // hang-safety escape
        }
        __builtin_amdgcn_fence(__ATOMIC_ACQUIRE, "agent");
    }
    __syncthreads();
}

__global__ __launch_bounds__(256, 3)
void gtcnn(const float* __restrict__ xin, const float* __restrict__ At,
           const float* __restrict__ As, const float* __restrict__ H,
           const float* __restrict__ svec, const float* __restrict__ Wf,
           const float* __restrict__ bf, const float* __restrict__ Wl,
           const float* __restrict__ bl, const float* __restrict__ mW1,
           const float* __restrict__ mb1, const float* __restrict__ mW2,
           const float* __restrict__ mb2, float* __restrict__ out,
           float* __restrict__ ws)
{
    __shared__ float smem[SMEMSZ];

    unsigned* cnt = (unsigned*)ws;
    float* dinv_t = ws + 64;       // 24
    float* dinv_s = ws + 96;       // 200
    float* X  = ws + 320;          // 153600 (updated in place)
    float* Y  = X  + NTOT;
    float* B1 = Y  + NTOT;
    float* Y2 = B1 + NTOT;

    unsigned lbar = 0;

    const int tid = threadIdx.x;
    const int bid = blockIdx.x;
    const int gid = bid*256 + tid;     // 0..153599, == element index
    const int t   = bid / 25;          // 25 blocks per t-slab
    const int sg  = bid % 25;
    const int sc  = sg*256 + tid;      // s*32+c within the t-slab
    const int idx = t*NSC + sc;        // == gid
    const int r   = tid >> 5;          // local s (0..7)
    const int c   = tid & 31;          // channel
    const int s   = sg*8 + r;          // global s (0..199)

    // ---------------- P0: dinv_t, dinv_s, X = xin@Wf + bf ----------------
    {
        const int wid = gid >> 6, lane = gid & 63;
        if (wid < TT) {
            float v = (lane < TT) ? At[wid*TT + lane] : 0.f;
            #pragma unroll
            for (int off = 32; off; off >>= 1) v += __shfl_xor(v, off, 64);
            if (lane == 0) dinv_t[wid] = 1.f / sqrtf(v);
        } else if (wid < TT + SS) {
            const int row = wid - TT;
            float v = 0.f;
            for (int j = lane; j < SS; j += 64) v += As[row*SS + j];
            #pragma unroll
            for (int off = 32; off; off >>= 1) v += __shfl_xor(v, off, 64);
            if (lane == 0) dinv_s[row] = 1.f / sqrtf(v);
        }
        const int n = gid >> 5;
        float acc = bf[c];
        #pragma unroll
        for (int i = 0; i < CIN; ++i) acc += xin[n*CIN + i] * Wf[i*CW + c];
        X[gid] = acc;
    }
    gridbar(cnt, &lbar);

    for (int b = 0; b < 2; ++b) {
        const float s0 = svec[b*4+0], s1 = svec[b*4+1];
        const float s2 = svec[b*4+2], s3 = svec[b*4+3];
        const float* Hb = H   + b*3*CW*CW;
        const float* W1 = mW1 + b*(CW+CIN)*CW;
        const float* b1 = mb1 + b*CW;
        const float* W2 = mW2 + b*CW*CW;
        const float* b2 = mb2 + b*CW;

        // ---------------- P1: Y = Ãs X  (dinv folded at staging) ----------------
        for (int i = tid; i < NSC; i += 256)
            smem[HOFF + i] = X[t*NSC + i] * dinv_s[i >> 5];
        __syncthreads();
        {
            const float4* arow = (const float4*)(As + s*SS);
            float acc = 0.f;
            #pragma unroll 5
            for (int q = 0; q < SS/4; ++q) {
                float4 a = arow[q];
                acc += a.x * smem[HOFF + (4*q+0)*CW + c];
                acc += a.y * smem[HOFF + (4*q+1)*CW + c];
                acc += a.z * smem[HOFF + (4*q+2)*CW + c];
                acc += a.w * smem[HOFF + (4*q+3)*CW + c];
            }
            Y[idx] = 0.5f * dinv_s[s] * acc;
        }
        gridbar(cnt, &lbar);

        // ---------------- P2: B1 = s0*X + s1*Y + s2*Ât X + s3*Ât Y ----------------
        if (tid < TT) smem[tid] = At[t*TT + tid] * dinv_t[t] * dinv_t[tid] * 0.5f;
        __syncthreads();
        {
            float z = 0.f, w = 0.f;
            #pragma unroll
            for (int tp = 0; tp < TT; ++tp) {
                const float a = smem[tp];
                z += a * X[tp*NSC + sc];
                w += a * Y[tp*NSC + sc];
            }
            B1[idx] = s0*X[idx] + s1*Y[idx] + s2*z + s3*w;
        }
        gridbar(cnt, &lbar);

        // ---------------- P3: Y2 = Ãs B1 ----------------
        for (int i = tid; i < NSC; i += 256)
            smem[HOFF + i] = B1[t*NSC + i] * dinv_s[i >> 5];
        __syncthreads();
        {
            const float4* arow = (const float4*)(As + s*SS);
            float acc = 0.f;
            #pragma unroll 5
            for (int q = 0; q < SS/4; ++q) {
                float4 a = arow[q];
                acc += a.x * smem[HOFF + (4*q+0)*CW + c];
                acc += a.y * smem[HOFF + (4*q+1)*CW + c];
                acc += a.z * smem[HOFF + (4*q+2)*CW + c];
                acc += a.w * smem[HOFF + (4*q+3)*CW + c];
            }
            Y2[idx] = 0.5f * dinv_s[s] * acc;
        }
        gridbar(cnt, &lbar);

        // ---------------- P4: temporal2 + epilogue (+ last for b==1) --------------
        // smem[0..23] still holds the Ât row staged in P2 (P3 only wrote HOFF+).
        for (int i = tid; i < 3*CW*CW; i += 256) smem[HOFF + i]  = Hb[i];
        for (int i = tid; i < (CW+CIN)*CW; i += 256) smem[W1OFF + i] = W1[i];
        for (int i = tid; i < CW*CW; i += 256) smem[W2OFF + i] = W2[i];
        if (tid < CW) { smem[B1OFF + tid] = b1[tid]; smem[B2OFF + tid] = b2[tid]; }
        {
            float z = 0.f, w = 0.f;
            #pragma unroll
            for (int tp = 0; tp < TT; ++tp) {
                const float a = smem[tp];
                z += a * B1[tp*NSC + sc];
                w += a * Y2[tp*NSC + sc];
            }
            const float p2 = s0*B1[idx] + s1*Y2[idx] + s2*z + s3*w;
            smem[SXOFF + tid]  = X[idx];
            smem[SP1OFF + tid] = B1[idx];
            smem[SP2OFF + tid] = p2;
            if (c < CIN) smem[SXINOFF + r*CIN + c] = xin[(idx >> 5)*CIN + c];
        }
        __syncthreads();
        {
            float acc = 0.f;
            #pragma unroll 8
            for (int cp = 0; cp < CW; ++cp) {
                acc += smem[SXOFF  + r*CW + cp] * smem[HOFF + cp*CW + c];
                acc += smem[SP1OFF + r*CW + cp] * smem[HOFF + CW*CW + cp*CW + c];
                acc += smem[SP2OFF + r*CW + cp] * smem[HOFF + 2*CW*CW + cp*CW + c];
            }
            smem[SXTOFF + tid] = tanhf(acc);
        }
        __syncthreads();
        {
            float h = smem[B1OFF + c];
            #pragma unroll 8
            for (int cp = 0; cp < CW; ++cp)
                h += smem[SXTOFF + r*CW + cp] * smem[W1OFF + cp*CW + c];
            #pragma unroll
            for (int i = 0; i < CIN; ++i)
                h += smem[SXINOFF + r*CIN + i] * smem[W1OFF + (CW+i)*CW + c];
            smem[SHOFF + tid] = fmaxf(h, 0.f);
        }
        __syncthreads();
        {
            float xn = smem[B2OFF + c];
            #pragma unroll 8
            for (int cp = 0; cp < CW; ++cp)
                xn += smem[SHOFF + r*CW + cp] * smem[W2OFF + cp*CW + c];
            if (b == 0) {
                X[idx] = xn;
            } else {
                float v = xn * Wl[c];
                #pragma unroll
                for (int off = 16; off; off >>= 1) v += __shfl_xor(v, off, 64);
                if (c == 0) out[idx >> 5] = v + bl[0];
            }
        }
        if (b == 0) gridbar(cnt, &lbar);
    }
}

extern "C" void kernel_launch(void* const* d_in, const int* in_sizes, int n_in,
                              void* d_out, int out_size, void* d_ws, size_t ws_size,
                              hipStream_t stream) {
    const float* xin   = (const float*)d_in[0];
    const float* Adj_t = (const float*)d_in[1];
    const float* Adj_s = (const float*)d_in[2];
    const float* H     = (const float*)d_in[3];
    const float* svec  = (const float*)d_in[4];
    const float* Wf    = (const float*)d_in[5];
    const float* bf    = (const float*)d_in[6];
    const float* Wl    = (const float*)d_in[7];
    const float* bl    = (const float*)d_in[8];
    const float* mW1   = (const float*)d_in[9];
    const float* mb1   = (const float*)d_in[10];
    const float* mW2   = (const float*)d_in[11];
    const float* mb2   = (const float*)d_in[12];
    float* out = (float*)d_out;
    float* ws  = (float*)d_ws;

    k_barinit<<<1, 1, 0, stream>>>((unsigned*)ws);
    gtcnn<<<NBLK, 256, 0, stream>>>(xin, Adj_t, Adj_s, H, svec, Wf, bf,
                                    Wl, bl, mW1, mb1, mW2, mb2, out, ws);
}

// Round 6
// 74.028 us; speedup vs baseline: 11.6835x; 6.9151x over previous
//
#include <hip/hip_runtime.h>
#include <math.h>

#define TT 24
#define SS 200
#define CIN 8
#define CW 32
#define NSC 6400      // SS*CW
#define NTOT 153600   // TT*SS*CW

// ws layout (float offsets)
#define DTOFF   0       // dinv_t [24]
#define DSOFF   32      // dinv_s [200]
#define DS2OFF  288     // dinv_s^2 [200]
#define ATOFF   512     // At-hat [576]
#define AT2OFF  1088    // At-hat^2 [576]
#define AS2OFF  2048    // As-hat^2 [40000]
#define XOFF    42048   // X (U0) [153600]
#define M0AOFF  195648
#define M0BOFF  349248
#define M1OFF   502848
#define M2OFF   656448
#define M3OFF   810048  // end 963648 floats ~ 3.86 MB

// ---------------- k0: X = xin@Wf+bf  (blocks 0..599); prep (block 600) ---
__global__ void k0(const float* __restrict__ xin, const float* __restrict__ Wf,
                   const float* __restrict__ bf, const float* __restrict__ At,
                   const float* __restrict__ As, float* __restrict__ ws) {
    __shared__ float sAt[TT*TT];
    __shared__ float sdt[TT];
    const int tid = threadIdx.x;
    if (blockIdx.x < 600) {
        const int gid = blockIdx.x*256 + tid;
        const int n = gid >> 5, c = gid & 31;
        float acc = bf[c];
        #pragma unroll
        for (int i = 0; i < CIN; ++i) acc += xin[n*CIN + i] * Wf[i*CW + c];
        ws[XOFF + gid] = acc;
        return;
    }
    // block 600: dinv_t, dinv_s, dinv_s^2, At-hat, At-hat^2
    if (tid < TT) {
        float sum = 0.f;
        for (int j = 0; j < TT; ++j) sum += At[tid*TT + j];
        const float d = 1.f / sqrtf(sum);
        sdt[tid] = d;
        ws[DTOFF + tid] = d;
    } else if (tid >= 32 && tid < 32 + SS) {
        const int i = tid - 32;
        float sum = 0.f;
        for (int j = 0; j < SS; ++j) sum += As[i*SS + j];
        const float d = 1.f / sqrtf(sum);
        ws[DSOFF + i] = d;
        ws[DS2OFF + i] = d * d;
    }
    __syncthreads();
    // R5 bug: TT*TT=576 > 256 threads; must LOOP, not guard.
    for (int i = tid; i < TT*TT; i += 256) {
        const int t = i / TT, tp = i % TT;
        const float v = At[i] * sdt[t] * sdt[tp] * 0.5f;
        sAt[i] = v;
        ws[ATOFF + i] = v;
    }
    __syncthreads();
    for (int i = tid; i < TT*TT; i += 256) {
        const int t = i / TT, tp = i % TT;
        float acc = 0.f;
        #pragma unroll
        for (int k = 0; k < TT; ++k) acc += sAt[t*TT + k] * sAt[k*TT + tp];
        ws[AT2OFF + i] = acc;
    }
}

// ---------------- k2: As-hat^2[i,j] = 0.25 d_i d_j sum_k As[i,k]As[j,k]d2[k]
__global__ void k2(const float* __restrict__ As, float* __restrict__ ws) {
    const int gid = blockIdx.x*256 + threadIdx.x;
    if (gid >= SS*SS) return;
    const int i = gid / SS, j = gid % SS;
    const float4* ri = (const float4*)(As + i*SS);
    const float4* rj = (const float4*)(As + j*SS);
    const float4* d2 = (const float4*)(ws + DS2OFF);
    float acc = 0.f;
    #pragma unroll 5
    for (int q = 0; q < SS/4; ++q) {
        const float4 a = ri[q], b = rj[q], d = d2[q];
        acc += a.x*b.x*d.x + a.y*b.y*d.y + a.z*b.z*d.z + a.w*b.w*d.w;
    }
    ws[AS2OFF + gid] = 0.25f * ws[DSOFF + i] * ws[DSOFF + j] * acc;
}

// ---------------- kA: spatial U1,U2 + fold into M0a,M0b,M1,M2,M3 ----------
__global__ __launch_bounds__(256)
void kA(const float* __restrict__ As, const float* __restrict__ svec,
        float* __restrict__ ws, int b) {
    const int gid = blockIdx.x*256 + threadIdx.x;
    const int t = gid / NSC;
    const int sc = gid - t*NSC;
    const int s = sc >> 5, c = sc & 31;

    const float s0 = svec[b*4+0], s1 = svec[b*4+1];
    const float s2 = svec[b*4+2], s3 = svec[b*4+3];
    const float b00 = s0*s0, b01 = 2.f*s0*s1, b02 = s1*s1;
    const float b10 = 2.f*s0*s2, b11 = 2.f*(s0*s3 + s1*s2), b12 = 2.f*s1*s3;
    const float b20 = s2*s2, b21 = 2.f*s2*s3, b22 = s3*s3;

    const float* X = ws + XOFF;
    const float4* ra  = (const float4*)(As + s*SS);          // raw As row s
    const float4* rq  = (const float4*)(ws + AS2OFF + s*SS); // As-hat^2 row s
    const float4* dk4 = (const float4*)(ws + DSOFF);
    const float* xcol = X + t*NSC + c;

    float u1 = 0.f, u2 = 0.f;
    #pragma unroll 5
    for (int q = 0; q < SS/4; ++q) {
        const float4 a = ra[q], w2 = rq[q], d = dk4[q];
        const float x0 = xcol[(4*q+0)*CW], x1 = xcol[(4*q+1)*CW];
        const float x2v = xcol[(4*q+2)*CW], x3 = xcol[(4*q+3)*CW];
        u1 += a.x*(d.x*x0) + a.y*(d.y*x1) + a.z*(d.z*x2v) + a.w*(d.w*x3);
        u2 += w2.x*x0 + w2.y*x1 + w2.z*x2v + w2.w*x3;
    }
    u1 *= 0.5f * ws[DSOFF + s];
    const float x0v = X[gid];

    ws[M0AOFF + gid] = s0*x0v + s1*u1;
    ws[M0BOFF + gid] = b00*x0v + b01*u1 + b02*u2;
    ws[M1OFF  + gid] = s2*x0v + s3*u1;
    ws[M2OFF  + gid] = b10*x0v + b11*u1 + b12*u2;
    ws[M3OFF  + gid] = b20*x0v + b21*u1 + b22*u2;
}

// ---------------- kB: temporal dots + epilogue (+ final out for last) -----
__global__ __launch_bounds__(256)
void kB(const float* __restrict__ xin, const float* __restrict__ H,
        const float* __restrict__ mW1, const float* __restrict__ mb1,
        const float* __restrict__ mW2, const float* __restrict__ mb2,
        const float* __restrict__ Wl, const float* __restrict__ bl,
        float* __restrict__ ws, float* __restrict__ out, int b, int last) {
    __shared__ float sAt[2*TT*TT];     // At-hat, At-hat^2
    __shared__ float sH[3*CW*CW];
    __shared__ float sW1[(CW+CIN)*CW];
    __shared__ float sW2[CW*CW];
    __shared__ float sb1[CW], sb2[CW];
    __shared__ float sx[256], sp1[256], sp2[256], sxt[256], sh[256];
    __shared__ float sxin[8*CIN];

    const int tid = threadIdx.x;
    const int gid = blockIdx.x*256 + tid;
    const int t = gid / NSC;           // block-uniform
    const int sc = gid - t*NSC;
    const int r = tid >> 5, c = tid & 31;
    const int node = gid >> 5;

    const float* Hb = H   + b*3*CW*CW;
    const float* W1 = mW1 + b*(CW+CIN)*CW;
    const float* W2 = mW2 + b*CW*CW;

    for (int i = tid; i < 2*TT*TT; i += 256) sAt[i] = ws[ATOFF + i];
    for (int i = tid; i < 3*CW*CW; i += 256) sH[i] = Hb[i];
    for (int i = tid; i < (CW+CIN)*CW; i += 256) sW1[i] = W1[i];
    for (int i = tid; i < CW*CW; i += 256) sW2[i] = W2[i];
    if (tid < CW) { sb1[tid] = mb1[b*CW + tid]; sb2[tid] = mb2[b*CW + tid]; }
    sx[tid] = ws[XOFF + gid];
    if (c < CIN) sxin[r*CIN + c] = xin[node*CIN + c];
    __syncthreads();

    {
        const float* M1 = ws + M1OFF + sc;
        const float* M2 = ws + M2OFF + sc;
        const float* M3 = ws + M3OFF + sc;
        float d1 = 0.f, d2 = 0.f, d3 = 0.f;
        #pragma unroll
        for (int tp = 0; tp < TT; ++tp) {
            const float a1 = sAt[t*TT + tp];
            const float a2 = sAt[TT*TT + t*TT + tp];
            d1 += a1 * M1[tp*NSC];
            d2 += a1 * M2[tp*NSC];
            d3 += a2 * M3[tp*NSC];
        }
        sp1[tid] = ws[M0AOFF + gid] + d1;
        sp2[tid] = ws[M0BOFF + gid] + d2 + d3;
    }
    __syncthreads();
    {
        float acc = 0.f;
        #pragma unroll 8
        for (int cp = 0; cp < CW; ++cp) {
            acc += sx[r*CW + cp]  * sH[cp*CW + c];
            acc += sp1[r*CW + cp] * sH[CW*CW + cp*CW + c];
            acc += sp2[r*CW + cp] * sH[2*CW*CW + cp*CW + c];
        }
        sxt[tid] = tanhf(acc);
    }
    __syncthreads();
    {
        float h = sb1[c];
        #pragma unroll 8
        for (int cp = 0; cp < CW; ++cp) h += sxt[r*CW + cp] * sW1[cp*CW + c];
        #pragma unroll
        for (int i = 0; i < CIN; ++i) h += sxin[r*CIN + i] * sW1[(CW+i)*CW + c];
        sh[tid] = fmaxf(h, 0.f);
    }
    __syncthreads();
    {
        float xn = sb2[c];
        #pragma unroll 8
        for (int cp = 0; cp < CW; ++cp) xn += sh[r*CW + cp] * sW2[cp*CW + c];
        if (!last) {
            ws[XOFF + gid] = xn;
        } else {
            float v = xn * Wl[c];
            #pragma unroll
            for (int off = 16; off; off >>= 1) v += __shfl_xor(v, off, 64);
            if (c == 0) out[node] = v + bl[0];
        }
    }
}

extern "C" void kernel_launch(void* const* d_in, const int* in_sizes, int n_in,
                              void* d_out, int out_size, void* d_ws, size_t ws_size,
                              hipStream_t stream) {
    const float* xin   = (const float*)d_in[0];
    const float* Adj_t = (const float*)d_in[1];
    const float* Adj_s = (const float*)d_in[2];
    const float* H     = (const float*)d_in[3];
    const float* svec  = (const float*)d_in[4];
    const float* Wf    = (const float*)d_in[5];
    const float* bf    = (const float*)d_in[6];
    const float* Wl    = (const float*)d_in[7];
    const float* bl    = (const float*)d_in[8];
    const float* mW1   = (const float*)d_in[9];
    const float* mb1   = (const float*)d_in[10];
    const float* mW2   = (const float*)d_in[11];
    const float* mb2   = (const float*)d_in[12];
    float* out = (float*)d_out;
    float* ws  = (float*)d_ws;

    k0<<<601, 256, 0, stream>>>(xin, Wf, bf, Adj_t, Adj_s, ws);
    k2<<<157, 256, 0, stream>>>(Adj_s, ws);
    for (int b = 0; b < 2; ++b) {
        kA<<<600, 256, 0, stream>>>(Adj_s, svec, ws, b);
        kB<<<600, 256, 0, stream>>>(xin, H, mW1, mb1, mW2, mb2, Wl, bl,
                                    ws, out, b, b == 1);
    }
}